// Round 1
// baseline (106.153 us; speedup 1.0000x reference)
//
#include <hip/hip_runtime.h>

// Shallow water RHS, N=4096, periodic BC, 2nd-order central differences.
// dh = -d1x((1+h)u) - d1y((1+h)v)
// du = MU*(d2x(u)+d2y(u)) - G*d1x(h)
// dv = MU*(d2x(v)+d2y(v)) - G*d1y(h)

constexpr int    NN      = 4096;
constexpr long   PLANE   = (long)NN * NN;
constexpr float  INV2DX  = 2048.0f;              // 1/(2*DX), DX = 1/N
constexpr float  MU_LAP  = 1e-4f * 16777216.0f;  // MU / DX^2
constexpr float  G2DX    = 9.8f * 2048.0f;       // G / (2*DX)

__global__ __launch_bounds__(256) void swm_rhs(const float* __restrict__ st,
                                               float* __restrict__ out) {
    const int i = blockIdx.y;
    const int j = (blockIdx.x * blockDim.x + threadIdx.x) * 4;

    const int im1 = (i == 0) ? (NN - 1) : (i - 1);
    const int ip1 = (i == NN - 1) ? 0 : (i + 1);
    const int jm1 = (j == 0) ? (NN - 1) : (j - 1);
    const int jp4 = (j + 4 == NN) ? 0 : (j + 4);

    const float* __restrict__ h = st;
    const float* __restrict__ u = st + PLANE;
    const float* __restrict__ v = st + 2 * PLANE;

    const long rc = (long)i * NN;
    const long rn = (long)im1 * NN;  // "north" = i-1
    const long rs = (long)ip1 * NN;  // "south" = i+1

    // center rows (vector), vertical neighbors (vector), horizontal edges (scalar)
    const float4 hC = *(const float4*)(h + rc + j);
    const float4 uC = *(const float4*)(u + rc + j);
    const float4 vC = *(const float4*)(v + rc + j);
    const float4 hN = *(const float4*)(h + rn + j);
    const float4 uN = *(const float4*)(u + rn + j);
    const float4 vN = *(const float4*)(v + rn + j);
    const float4 hS = *(const float4*)(h + rs + j);
    const float4 uS = *(const float4*)(u + rs + j);
    const float4 vS = *(const float4*)(v + rs + j);
    const float hL = h[rc + jm1], hR = h[rc + jp4];
    const float uL = u[rc + jm1], uR = u[rc + jp4];
    const float vL = v[rc + jm1], vR = v[rc + jp4];

    // horizontal 6-point windows (fully unrolled below -> stays in registers)
    const float hx[6] = {hL, hC.x, hC.y, hC.z, hC.w, hR};
    const float ux[6] = {uL, uC.x, uC.y, uC.z, uC.w, uR};
    const float vx[6] = {vL, vC.x, vC.y, vC.z, vC.w, vR};
    const float hn[4] = {hN.x, hN.y, hN.z, hN.w};
    const float un[4] = {uN.x, uN.y, uN.z, uN.w};
    const float vn[4] = {vN.x, vN.y, vN.z, vN.w};
    const float hs[4] = {hS.x, hS.y, hS.z, hS.w};
    const float us[4] = {uS.x, uS.y, uS.z, uS.w};
    const float vs[4] = {vS.x, vS.y, vS.z, vS.w};

    float rh[4], ru[4], rv[4];
#pragma unroll
    for (int k = 0; k < 4; ++k) {
        const float hl = hx[k], hc = hx[k + 1], hr = hx[k + 2];
        const float ul = ux[k], uc = ux[k + 1], ur = ux[k + 2];
        const float vl = vx[k], vc = vx[k + 1], vr = vx[k + 2];
        const float hu = hn[k], hd = hs[k];
        const float uu = un[k], ud = us[k];
        const float vu = vn[k], vd = vs[k];
        (void)hc;

        rh[k] = -INV2DX * (((1.0f + hr) * ur - (1.0f + hl) * ul)
                         + ((1.0f + hd) * vd - (1.0f + hu) * vu));
        ru[k] = MU_LAP * (ul + ur + uu + ud - 4.0f * uc) - G2DX * (hr - hl);
        rv[k] = MU_LAP * (vl + vr + vu + vd - 4.0f * vc) - G2DX * (hd - hu);
    }

    *(float4*)(out + rc + j)             = make_float4(rh[0], rh[1], rh[2], rh[3]);
    *(float4*)(out + PLANE + rc + j)     = make_float4(ru[0], ru[1], ru[2], ru[3]);
    *(float4*)(out + 2 * PLANE + rc + j) = make_float4(rv[0], rv[1], rv[2], rv[3]);
}

extern "C" void kernel_launch(void* const* d_in, const int* in_sizes, int n_in,
                              void* d_out, int out_size, void* d_ws, size_t ws_size,
                              hipStream_t stream) {
    // d_in[0] = t (scalar, unused by RHS), d_in[1] = state [3,N,N] fp32
    const float* state = (const float*)d_in[1];
    float* out = (float*)d_out;
    dim3 block(256);
    dim3 grid(NN / 4 / 256, NN);  // 4 x 4096 blocks
    swm_rhs<<<grid, block, 0, stream>>>(state, out);
}

// Round 2
// 88.250 us; speedup vs baseline: 1.2029x; 1.2029x over previous
//
#include <hip/hip_runtime.h>

// Shallow water RHS, N=4096, periodic BC, 2nd-order central differences.
// dh = -d1x((1+h)u) - d1y((1+h)v)
// du = MU*(d2x(u)+d2y(u)) - G*d1x(h)
// dv = MU*(d2x(v)+d2y(v)) - G*d1y(h)
//
// Round 2: register row-blocking (RPT rows/thread, rolling 3-row window)
// + shuffle-based horizontal neighbors (wave-edge lanes fall back to loads).

constexpr int    NN      = 4096;
constexpr long   PLANE   = (long)NN * NN;
constexpr float  INV2DX  = 2048.0f;              // 1/(2*DX), DX = 1/N
constexpr float  MU_LAP  = 1e-4f * 16777216.0f;  // MU / DX^2
constexpr float  G2DX    = 9.8f * 2048.0f;       // G / (2*DX)
constexpr int    RPT     = 4;                    // rows per thread

__global__ __launch_bounds__(256) void swm_rhs(const float* __restrict__ st,
                                               float* __restrict__ out) {
    const int tid  = threadIdx.x;
    const int lane = tid & 63;
    const int j    = (blockIdx.x * blockDim.x + tid) * 4;
    const int i0   = blockIdx.y * RPT;

    const int jm1 = (j == 0) ? (NN - 1) : (j - 1);
    const int jp4 = (j + 4 == NN) ? 0 : (j + 4);

    const float* __restrict__ h = st;
    const float* __restrict__ u = st + PLANE;
    const float* __restrict__ v = st + 2 * PLANE;

    auto ld4 = [&](const float* __restrict__ p, int row) -> float4 {
        return *(const float4*)(p + (long)row * NN + j);
    };

    // rolling 3-row window: P (i-1), C (i), S (i+1)
    const int im1 = (i0 == 0) ? (NN - 1) : (i0 - 1);
    float4 hP = ld4(h, im1), uP = ld4(u, im1), vP = ld4(v, im1);
    float4 hC = ld4(h, i0),  uC = ld4(u, i0),  vC = ld4(v, i0);

#pragma unroll
    for (int r = 0; r < RPT; ++r) {
        const int i   = i0 + r;
        const int ip1 = (i + 1 == NN) ? 0 : (i + 1);
        const float4 hS = ld4(h, ip1), uS = ld4(u, ip1), vS = ld4(v, ip1);
        const long rc = (long)i * NN;

        // horizontal neighbors: adjacent lanes hold them in registers
        float hL = __shfl_up(hC.w, 1);
        float uL = __shfl_up(uC.w, 1);
        float vL = __shfl_up(vC.w, 1);
        float hR = __shfl_down(hC.x, 1);
        float uR = __shfl_down(uC.x, 1);
        float vR = __shfl_down(vC.x, 1);
        if (lane == 0)  { hL = h[rc + jm1]; uL = u[rc + jm1]; vL = v[rc + jm1]; }
        if (lane == 63) { hR = h[rc + jp4]; uR = u[rc + jp4]; vR = v[rc + jp4]; }

        const float hx[6] = {hL, hC.x, hC.y, hC.z, hC.w, hR};
        const float ux[6] = {uL, uC.x, uC.y, uC.z, uC.w, uR};
        const float vx[6] = {vL, vC.x, vC.y, vC.z, vC.w, vR};
        const float hn[4] = {hP.x, hP.y, hP.z, hP.w};
        const float un[4] = {uP.x, uP.y, uP.z, uP.w};
        const float vn[4] = {vP.x, vP.y, vP.z, vP.w};
        const float hs[4] = {hS.x, hS.y, hS.z, hS.w};
        const float us[4] = {uS.x, uS.y, uS.z, uS.w};
        const float vs[4] = {vS.x, vS.y, vS.z, vS.w};

        float rh[4], ru[4], rv[4];
#pragma unroll
        for (int k = 0; k < 4; ++k) {
            const float hl = hx[k], hr = hx[k + 2];
            const float ul = ux[k], uc = ux[k + 1], ur = ux[k + 2];
            const float vl = vx[k], vc = vx[k + 1], vr = vx[k + 2];
            const float hu = hn[k], hd = hs[k];
            const float uu = un[k], ud = us[k];
            const float vu = vn[k], vd = vs[k];

            rh[k] = -INV2DX * (((1.0f + hr) * ur - (1.0f + hl) * ul)
                             + ((1.0f + hd) * vd - (1.0f + hu) * vu));
            ru[k] = MU_LAP * (ul + ur + uu + ud - 4.0f * uc) - G2DX * (hr - hl);
            rv[k] = MU_LAP * (vl + vr + vu + vd - 4.0f * vc) - G2DX * (hd - hu);
        }

        *(float4*)(out + rc + j)             = make_float4(rh[0], rh[1], rh[2], rh[3]);
        *(float4*)(out + PLANE + rc + j)     = make_float4(ru[0], ru[1], ru[2], ru[3]);
        *(float4*)(out + 2 * PLANE + rc + j) = make_float4(rv[0], rv[1], rv[2], rv[3]);

        hP = hC; hC = hS;
        uP = uC; uC = uS;
        vP = vC; vC = vS;
    }
}

extern "C" void kernel_launch(void* const* d_in, const int* in_sizes, int n_in,
                              void* d_out, int out_size, void* d_ws, size_t ws_size,
                              hipStream_t stream) {
    // d_in[0] = t (scalar, unused by RHS), d_in[1] = state [3,N,N] fp32
    const float* state = (const float*)d_in[1];
    float* out = (float*)d_out;
    dim3 block(256);
    dim3 grid(NN / 4 / 256, NN / RPT);  // 4 x 1024 blocks
    swm_rhs<<<grid, block, 0, stream>>>(state, out);
}

// Round 3
// 80.930 us; speedup vs baseline: 1.3117x; 1.0904x over previous
//
#include <hip/hip_runtime.h>

// Shallow water RHS, N=4096, periodic BC, 2nd-order central differences.
// dh = -d1x((1+h)u) - d1y((1+h)v)
// du = MU*(d2x(u)+d2y(u)) - G*d1x(h)
// dv = MU*(d2x(v)+d2y(v)) - G*d1y(h)
//
// Round 3: edge (wrap-column) loads hoisted out of the row loop — one masked
// load per plane/row covers lane0-left + lane63-right; inner loop is 3
// dwordx4 loads + 6 shuffles + 3 nontemporal dwordx4 stores per iteration.

typedef float f4 __attribute__((ext_vector_type(4)));

constexpr int    NN      = 4096;
constexpr long   PLANE   = (long)NN * NN;
constexpr float  INV2DX  = 2048.0f;              // 1/(2*DX), DX = 1/N
constexpr float  MU_LAP  = 1e-4f * 16777216.0f;  // MU / DX^2
constexpr float  G2DX    = 9.8f * 2048.0f;       // G / (2*DX)
constexpr int    RPT     = 4;                    // rows per thread

__global__ __launch_bounds__(256) void swm_rhs(const float* __restrict__ st,
                                               float* __restrict__ out) {
    const int tid  = threadIdx.x;
    const int lane = tid & 63;
    const int j    = (blockIdx.x * blockDim.x + tid) * 4;
    const int i0   = blockIdx.y * RPT;

    const float* __restrict__ h = st;
    const float* __restrict__ u = st + PLANE;
    const float* __restrict__ v = st + 2 * PLANE;

    // --- hoisted edge loads: lane 0 reads the left-wrap column, lane 63 the
    // right-wrap column; same instruction, per-lane address. Other lanes: unused.
    const int jl = (j == 0) ? NN - 1 : j - 1;
    const int jr = (j + 4 == NN) ? 0 : j + 4;
    const long ecol = (lane == 0) ? jl : jr;
    float eh[RPT] = {}, eu[RPT] = {}, ev[RPT] = {};
    if (lane == 0 || lane == 63) {
#pragma unroll
        for (int r = 0; r < RPT; ++r) {
            const long off = (long)(i0 + r) * NN + ecol;
            eh[r] = h[off]; eu[r] = u[off]; ev[r] = v[off];
        }
    }

    auto ld4 = [&](const float* __restrict__ p, int row) -> f4 {
        return *(const f4*)(p + (long)row * NN + j);
    };

    // rolling 3-row window: P (i-1), C (i), S (i+1)
    const int im1 = (i0 == 0) ? NN - 1 : i0 - 1;
    f4 hP = ld4(h, im1), uP = ld4(u, im1), vP = ld4(v, im1);
    f4 hC = ld4(h, i0),  uC = ld4(u, i0),  vC = ld4(v, i0);

#pragma unroll
    for (int r = 0; r < RPT; ++r) {
        const int i   = i0 + r;
        const int ip1 = (i + 1 == NN) ? 0 : i + 1;
        const f4 hS = ld4(h, ip1), uS = ld4(u, ip1), vS = ld4(v, ip1);
        const long rc = (long)i * NN + j;

        // horizontal neighbors from adjacent lanes; wave-edge lanes use
        // the preloaded wrap values.
        float hL = __shfl_up(hC[3], 1);
        float uL = __shfl_up(uC[3], 1);
        float vL = __shfl_up(vC[3], 1);
        float hR = __shfl_down(hC[0], 1);
        float uR = __shfl_down(uC[0], 1);
        float vR = __shfl_down(vC[0], 1);
        if (lane == 0)  { hL = eh[r]; uL = eu[r]; vL = ev[r]; }
        if (lane == 63) { hR = eh[r]; uR = eu[r]; vR = ev[r]; }

        const float hx[6] = {hL, hC[0], hC[1], hC[2], hC[3], hR};
        const float ux[6] = {uL, uC[0], uC[1], uC[2], uC[3], uR};
        const float vx[6] = {vL, vC[0], vC[1], vC[2], vC[3], vR};

        f4 rh, ru, rv;
#pragma unroll
        for (int k = 0; k < 4; ++k) {
            const float hl = hx[k], hr = hx[k + 2];
            const float ul = ux[k], uc = ux[k + 1], ur = ux[k + 2];
            const float vl = vx[k], vc = vx[k + 1], vr = vx[k + 2];
            const float hu = hP[k], hd = hS[k];
            const float uu = uP[k], ud = uS[k];
            const float vu = vP[k], vd = vS[k];

            rh[k] = -INV2DX * (((1.0f + hr) * ur - (1.0f + hl) * ul)
                             + ((1.0f + hd) * vd - (1.0f + hu) * vu));
            ru[k] = MU_LAP * (ul + ur + uu + ud - 4.0f * uc) - G2DX * (hr - hl);
            rv[k] = MU_LAP * (vl + vr + vu + vd - 4.0f * vc) - G2DX * (hd - hu);
        }

        // outputs are write-once: nontemporal to keep L2 for the reused inputs
        __builtin_nontemporal_store(rh, (f4*)(out + rc));
        __builtin_nontemporal_store(ru, (f4*)(out + PLANE + rc));
        __builtin_nontemporal_store(rv, (f4*)(out + 2 * PLANE + rc));

        hP = hC; hC = hS;
        uP = uC; uC = uS;
        vP = vC; vC = vS;
    }
}

extern "C" void kernel_launch(void* const* d_in, const int* in_sizes, int n_in,
                              void* d_out, int out_size, void* d_ws, size_t ws_size,
                              hipStream_t stream) {
    // d_in[0] = t (scalar, unused by RHS), d_in[1] = state [3,N,N] fp32
    const float* state = (const float*)d_in[1];
    float* out = (float*)d_out;
    dim3 block(256);
    dim3 grid(NN / 4 / 256, NN / RPT);  // 4 x 1024 blocks
    swm_rhs<<<grid, block, 0, stream>>>(state, out);
}

// Round 4
// 77.758 us; speedup vs baseline: 1.3652x; 1.0408x over previous
//
#include <hip/hip_runtime.h>

// Shallow water RHS, N=4096, periodic BC, 2nd-order central differences.
// dh = -d1x((1+h)u) - d1y((1+h)v)
// du = MU*(d2x(u)+d2y(u)) - G*d1x(h)
// dv = MU*(d2x(v)+d2y(v)) - G*d1y(h)
//
// Round 4: all-upfront loads. 18 dwordx4 row loads + 12 masked edge loads
// issued before any compute -> deep VMEM pipe, single drain, no per-row
// latency bubbles. Trades VGPR (occupancy) for ILP.

typedef float f4 __attribute__((ext_vector_type(4)));

constexpr int    NN      = 4096;
constexpr long   PLANE   = (long)NN * NN;
constexpr float  INV2DX  = 2048.0f;              // 1/(2*DX), DX = 1/N
constexpr float  MU_LAP  = 1e-4f * 16777216.0f;  // MU / DX^2
constexpr float  G2DX    = 9.8f * 2048.0f;       // G / (2*DX)
constexpr int    RPT     = 4;                    // rows per thread

__global__ __launch_bounds__(256) void swm_rhs(const float* __restrict__ st,
                                               float* __restrict__ out) {
    const int tid  = threadIdx.x;
    const int lane = tid & 63;
    const int j    = (blockIdx.x * blockDim.x + tid) * 4;
    const int i0   = blockIdx.y * RPT;

    const float* __restrict__ h = st;
    const float* __restrict__ u = st + PLANE;
    const float* __restrict__ v = st + 2 * PLANE;

    // --- all row loads up front: rows i0-1 .. i0+RPT, 3 planes, dwordx4 each
    f4 H[RPT + 2], U[RPT + 2], V[RPT + 2];
#pragma unroll
    for (int r = 0; r < RPT + 2; ++r) {
        int row = i0 + r - 1;
        row = (row < 0) ? NN - 1 : (row >= NN ? row - NN : row);
        const long off = (long)row * NN + j;
        H[r] = *(const f4*)(h + off);
        U[r] = *(const f4*)(u + off);
        V[r] = *(const f4*)(v + off);
    }

    // --- edge (wrap-column) loads: lane 0 needs left col, lane 63 right col.
    const int jl = (j == 0) ? NN - 1 : j - 1;
    const int jr = (j + 4 == NN) ? 0 : j + 4;
    const long ecol = (lane == 0) ? jl : jr;
    float eh[RPT] = {}, eu[RPT] = {}, ev[RPT] = {};
    if (lane == 0 || lane == 63) {
#pragma unroll
        for (int r = 0; r < RPT; ++r) {
            const long off = (long)(i0 + r) * NN + ecol;
            eh[r] = h[off]; eu[r] = u[off]; ev[r] = v[off];
        }
    }

#pragma unroll
    for (int r = 0; r < RPT; ++r) {
        const f4 hP = H[r], hC = H[r + 1], hS = H[r + 2];
        const f4 uP = U[r], uC = U[r + 1], uS = U[r + 2];
        const f4 vP = V[r], vC = V[r + 1], vS = V[r + 2];
        const long rc = (long)(i0 + r) * NN + j;

        float hL = __shfl_up(hC[3], 1);
        float uL = __shfl_up(uC[3], 1);
        float vL = __shfl_up(vC[3], 1);
        float hR = __shfl_down(hC[0], 1);
        float uR = __shfl_down(uC[0], 1);
        float vR = __shfl_down(vC[0], 1);
        if (lane == 0)  { hL = eh[r]; uL = eu[r]; vL = ev[r]; }
        if (lane == 63) { hR = eh[r]; uR = eu[r]; vR = ev[r]; }

        const float hx[6] = {hL, hC[0], hC[1], hC[2], hC[3], hR};
        const float ux[6] = {uL, uC[0], uC[1], uC[2], uC[3], uR};
        const float vx[6] = {vL, vC[0], vC[1], vC[2], vC[3], vR};

        f4 rh, ru, rv;
#pragma unroll
        for (int k = 0; k < 4; ++k) {
            const float hl = hx[k], hr = hx[k + 2];
            const float ul = ux[k], uc = ux[k + 1], ur = ux[k + 2];
            const float vl = vx[k], vc = vx[k + 1], vr = vx[k + 2];

            rh[k] = -INV2DX * (((1.0f + hr) * ur - (1.0f + hl) * ul)
                             + ((1.0f + hS[k]) * vS[k] - (1.0f + hP[k]) * vP[k]));
            ru[k] = MU_LAP * (ul + ur + uP[k] + uS[k] - 4.0f * uc) - G2DX * (hr - hl);
            rv[k] = MU_LAP * (vl + vr + vP[k] + vS[k] - 4.0f * vc) - G2DX * (hS[k] - hP[k]);
        }

        // outputs are write-once: nontemporal, keep L2 for reused input rows
        __builtin_nontemporal_store(rh, (f4*)(out + rc));
        __builtin_nontemporal_store(ru, (f4*)(out + PLANE + rc));
        __builtin_nontemporal_store(rv, (f4*)(out + 2 * PLANE + rc));
    }
}

extern "C" void kernel_launch(void* const* d_in, const int* in_sizes, int n_in,
                              void* d_out, int out_size, void* d_ws, size_t ws_size,
                              hipStream_t stream) {
    // d_in[0] = t (scalar, unused by RHS), d_in[1] = state [3,N,N] fp32
    const float* state = (const float*)d_in[1];
    float* out = (float*)d_out;
    dim3 block(256);
    dim3 grid(NN / 4 / 256, NN / RPT);  // 4 x 1024 blocks
    swm_rhs<<<grid, block, 0, stream>>>(state, out);
}

// Round 5
// 62.429 us; speedup vs baseline: 1.7004x; 1.2455x over previous
//
#include <hip/hip_runtime.h>

// Shallow water RHS, N=4096, periodic BC, 2nd-order central differences.
// dh = -d1x((1+h)u) - d1y((1+h)v)
// du = MU*(d2x(u)+d2y(u)) - G*d1x(h)
// dv = MU*(d2x(v)+d2y(v)) - G*d1y(h)
//
// Round 5: RPT=8 (halo overhead 1.5x -> 1.25x of read volume) + XCD band
// swizzle (vertical halo neighbors land on the same XCD's L2) + all-upfront
// loads + nontemporal stores.

typedef float f4 __attribute__((ext_vector_type(4)));

constexpr int    NN      = 4096;
constexpr long   PLANE   = (long)NN * NN;
constexpr float  INV2DX  = 2048.0f;              // 1/(2*DX), DX = 1/N
constexpr float  MU_LAP  = 1e-4f * 16777216.0f;  // MU / DX^2
constexpr float  G2DX    = 9.8f * 2048.0f;       // G / (2*DX)
constexpr int    RPT     = 8;                    // rows per thread
constexpr int    BX      = NN / (4 * 256);       // 4  x-blocks
constexpr int    BY      = NN / RPT;             // 512 y-blocks
constexpr int    NWG     = BX * BY;              // 2048 (divisible by 8 XCDs)

__global__ __launch_bounds__(256) void swm_rhs(const float* __restrict__ st,
                                               float* __restrict__ out) {
    // XCD band swizzle: hardware round-robins flat blockIdx across 8 XCDs;
    // remap so XCD k owns the contiguous y-band [k*BY/8, (k+1)*BY/8).
    const int flat = blockIdx.x;
    const int swz  = (flat & 7) * (NWG / 8) + (flat >> 3);
    const int bx   = swz & (BX - 1);
    const int by   = swz / BX;

    const int tid  = threadIdx.x;
    const int lane = tid & 63;
    const int j    = (bx * 256 + tid) * 4;
    const int i0   = by * RPT;

    const float* __restrict__ h = st;
    const float* __restrict__ u = st + PLANE;
    const float* __restrict__ v = st + 2 * PLANE;

    // --- all row loads up front: rows i0-1 .. i0+RPT, 3 planes, dwordx4 each
    f4 H[RPT + 2], U[RPT + 2], V[RPT + 2];
#pragma unroll
    for (int r = 0; r < RPT + 2; ++r) {
        int row = i0 + r - 1;
        row = (row < 0) ? NN - 1 : (row >= NN ? row - NN : row);
        const long off = (long)row * NN + j;
        H[r] = *(const f4*)(h + off);
        U[r] = *(const f4*)(u + off);
        V[r] = *(const f4*)(v + off);
    }

    // --- edge (wrap-column) loads: lane 0 needs left col, lane 63 right col.
    const int jl = (j == 0) ? NN - 1 : j - 1;
    const int jr = (j + 4 == NN) ? 0 : j + 4;
    const long ecol = (lane == 0) ? jl : jr;
    float eh[RPT] = {}, eu[RPT] = {}, ev[RPT] = {};
    if (lane == 0 || lane == 63) {
#pragma unroll
        for (int r = 0; r < RPT; ++r) {
            const long off = (long)(i0 + r) * NN + ecol;
            eh[r] = h[off]; eu[r] = u[off]; ev[r] = v[off];
        }
    }

#pragma unroll
    for (int r = 0; r < RPT; ++r) {
        const f4 hP = H[r], hC = H[r + 1], hS = H[r + 2];
        const f4 uP = U[r], uC = U[r + 1], uS = U[r + 2];
        const f4 vP = V[r], vC = V[r + 1], vS = V[r + 2];
        const long rc = (long)(i0 + r) * NN + j;

        float hL = __shfl_up(hC[3], 1);
        float uL = __shfl_up(uC[3], 1);
        float vL = __shfl_up(vC[3], 1);
        float hR = __shfl_down(hC[0], 1);
        float uR = __shfl_down(uC[0], 1);
        float vR = __shfl_down(vC[0], 1);
        if (lane == 0)  { hL = eh[r]; uL = eu[r]; vL = ev[r]; }
        if (lane == 63) { hR = eh[r]; uR = eu[r]; vR = ev[r]; }

        const float hx[6] = {hL, hC[0], hC[1], hC[2], hC[3], hR};
        const float ux[6] = {uL, uC[0], uC[1], uC[2], uC[3], uR};
        const float vx[6] = {vL, vC[0], vC[1], vC[2], vC[3], vR};

        f4 rh, ru, rv;
#pragma unroll
        for (int k = 0; k < 4; ++k) {
            const float hl = hx[k], hr = hx[k + 2];
            const float ul = ux[k], uc = ux[k + 1], ur = ux[k + 2];
            const float vl = vx[k], vc = vx[k + 1], vr = vx[k + 2];

            rh[k] = -INV2DX * (((1.0f + hr) * ur - (1.0f + hl) * ul)
                             + ((1.0f + hS[k]) * vS[k] - (1.0f + hP[k]) * vP[k]));
            ru[k] = MU_LAP * (ul + ur + uP[k] + uS[k] - 4.0f * uc) - G2DX * (hr - hl);
            rv[k] = MU_LAP * (vl + vr + vP[k] + vS[k] - 4.0f * vc) - G2DX * (hS[k] - hP[k]);
        }

        // outputs are write-once: nontemporal, keep L2/L3 for reused inputs
        __builtin_nontemporal_store(rh, (f4*)(out + rc));
        __builtin_nontemporal_store(ru, (f4*)(out + PLANE + rc));
        __builtin_nontemporal_store(rv, (f4*)(out + 2 * PLANE + rc));
    }
}

extern "C" void kernel_launch(void* const* d_in, const int* in_sizes, int n_in,
                              void* d_out, int out_size, void* d_ws, size_t ws_size,
                              hipStream_t stream) {
    // d_in[0] = t (scalar, unused by RHS), d_in[1] = state [3,N,N] fp32
    const float* state = (const float*)d_in[1];
    float* out = (float*)d_out;
    swm_rhs<<<dim3(NWG), dim3(256), 0, stream>>>(state, out);
}